// Round 8
// baseline (63759.015 us; speedup 1.0000x reference)
//
#include <hip/hip_runtime.h>

// ============================================================================
// Two-level LSTM (char k-mer LSTM -> word LSTM), MI355X.
//
// Persistent multi-WG recurrence kernels, all worker WGs elected onto ONE XCD.
// Exchange: tagged 8-byte slots ((t)<<32 | f32bits(h)), parity double-buffered,
// atomic swap publish / atomic or-0 poll (atomics execute at the TCC -- the
// only cross-CU-coherent primitive, per R2/R3). Per-consumer-WG replicas (R7).
//
// R8 changes (target: TCC same-line RMW serialization, the measured ~3000cyc
// step driver):
//  1. ONE SLOT PER LINE: char slots padded to 128 B, word to 32 B. Each
//     polled line serves 1 (char) / 4 (word) lanes instead of 16 -> the
//     line's RMW queue (~16-32cyc/atomic) collapses; probe RTT ~300-400cyc.
//  2. DEPTH-3 PIPELINED POLL (asm): 3 same-address or-0 probes in flight;
//     exit when the oldest completed probe has value >= (t<<32) on all lanes
//     (tags are monotone, so >= is sound). No drain at exit: probe regs stay
//     live across the step loop; strays are older than all subsequent vmem
//     (vmcnt waits oldest-first => conservative-safe); explicit vmcnt(0)
//     before kernel end. Discovery ~1.2 RTT instead of ~1.5-2 serial RTTs.
//  3. >= check is not 0xAA-poison-safe -> k_zero clears slot arrays each
//     launch (stream-ordered before the LSTM kernels; graph-replay safe).
// ============================================================================

#define S_LEN 4096
#define TCH   16384
#define ALPHA 25
#define ECH   64
#define HR    256
#define DL    128
#define EW    128
#define HW    512
#define NWC   16           // char worker WGs (16 units each)
#define GRIDC 128
#define NWW   32           // word worker WGs (16 units each)
#define GRIDW 256
#define SC_STRIDE 16       // u64s per char slot (128 B line)
#define SW_STRIDE 4        // u64s per word slot (32 B)

static __device__ __forceinline__ float fsigmoid(float x) {
  x = fminf(fmaxf(x, -30.f), 30.f);
  return __builtin_amdgcn_rcpf(1.0f + __expf(-x));
}
static __device__ __forceinline__ float ftanh(float x) {
  x = fminf(fmaxf(x, -15.f), 15.f);
  float e = __expf(2.0f * x);
  return 1.0f - 2.0f * __builtin_amdgcn_rcpf(e + 1.0f);
}

static __device__ __forceinline__ void barrier_lds() {
  asm volatile("s_waitcnt lgkmcnt(0)\n\ts_barrier" ::: "memory");
}

// Depth-3 pipelined poll. p0..p2 must be live across the caller's step loop.
// Accept condition: slot value >= thr (= t<<32); protocol guarantees the slot
// holds either (t-2)<<32|data or t<<32|data, and zeroed at launch.
static __device__ __forceinline__ unsigned long long poll3(
    unsigned long long* addr, unsigned long long thr,
    unsigned long long& p0, unsigned long long& p1, unsigned long long& p2) {
  unsigned long long out;
  unsigned long long zero = 0;
  unsigned long long sc;
  asm volatile(
    "global_atomic_or_x2 %[p0], %[ad], %[z], off sc0\n\t"
    "global_atomic_or_x2 %[p1], %[ad], %[z], off sc0\n\t"
    "global_atomic_or_x2 %[p2], %[ad], %[z], off sc0\n"
    "Lp_%=:\n\t"
    "s_waitcnt vmcnt(2)\n\t"
    "v_cmp_ge_u64 vcc, %[p0], %[th]\n\t"
    "s_andn2_b64 %[sc], exec, vcc\n\t"
    "s_cbranch_scc0 E0_%=\n\t"
    "global_atomic_or_x2 %[p0], %[ad], %[z], off sc0\n\t"
    "s_waitcnt vmcnt(2)\n\t"
    "v_cmp_ge_u64 vcc, %[p1], %[th]\n\t"
    "s_andn2_b64 %[sc], exec, vcc\n\t"
    "s_cbranch_scc0 E1_%=\n\t"
    "global_atomic_or_x2 %[p1], %[ad], %[z], off sc0\n\t"
    "s_waitcnt vmcnt(2)\n\t"
    "v_cmp_ge_u64 vcc, %[p2], %[th]\n\t"
    "s_andn2_b64 %[sc], exec, vcc\n\t"
    "s_cbranch_scc0 E2_%=\n\t"
    "global_atomic_or_x2 %[p2], %[ad], %[z], off sc0\n\t"
    "s_branch Lp_%=\n"
    "E0_%=:\n\t"
    "v_lshlrev_b64 %[o], 0, %[p0]\n\t"
    "s_branch Ed_%=\n"
    "E1_%=:\n\t"
    "v_lshlrev_b64 %[o], 0, %[p1]\n\t"
    "s_branch Ed_%=\n"
    "E2_%=:\n\t"
    "v_lshlrev_b64 %[o], 0, %[p2]\n"
    "Ed_%=:"
    : [p0]"+v"(p0), [p1]"+v"(p1), [p2]"+v"(p2), [o]"=v"(out), [sc]"=s"(sc)
    : [ad]"v"(addr), [z]"v"(zero), [th]"s"(thr)
    : "vcc", "scc");
  return out;
}

// Publish: fire-and-forget swap at the TCC. Volatile-asm ordering keeps it
// between this step's barrier and the next step's poll.
static __device__ __forceinline__ void atom_swap(
    unsigned long long* p, unsigned long long v) {
  asm volatile("global_atomic_swap_x2 %0, %1, off" :: "v"(p), "v"(v));
}
static __device__ __forceinline__ void drain_vm() {
  asm volatile("s_waitcnt vmcnt(0)" ::: "memory");
}

// Deadlock-free single-XCD role election (R4-proven).
static __device__ __forceinline__ int elect_role(int* el, int NW) {
  unsigned xcd;
  asm volatile("s_getreg_b32 %0, hwreg(HW_REG_XCC_ID)" : "=s"(xcd));
  xcd &= 7u;
  int r = __hip_atomic_fetch_add(&el[xcd], 1, __ATOMIC_RELAXED,
                                 __HIP_MEMORY_SCOPE_AGENT);
  if (r == NW - 1) {
    int exp = -1;
    __hip_atomic_compare_exchange_strong(&el[8], &exp, (int)xcd,
        __ATOMIC_RELAXED, __ATOMIC_RELAXED, __HIP_MEMORY_SCOPE_AGENT);
  }
  int w;
  while ((w = __hip_atomic_load(&el[8], __ATOMIC_RELAXED,
                                __HIP_MEMORY_SCOPE_AGENT)) < 0) {}
  if (w != (int)xcd) return -1;
  int rr = __hip_atomic_fetch_add(&el[9], 1, __ATOMIC_RELAXED,
                                  __HIP_MEMORY_SCOPE_AGENT);
  return (rr < NW) ? rr : -1;
}

__global__ void k_init(int* ec, int* ew) {
  int t = threadIdx.x;
  if (t < 10) ec[t] = (t == 8) ? -1 : 0;
  else if (t < 20) { int u = t - 10; ew[u] = (u == 8) ? -1 : 0; }
}

// Zero the 2 MB slot region (>=-check is not poison-safe). 512x256x16B = 2MB.
__global__ void k_zero(float4* base) {
  base[blockIdx.x * 256 + threadIdx.x] = float4{0.f, 0.f, 0.f, 0.f};
}

// ---------------------------------------------------------------------------
// K1a: char gate-input table.
// ---------------------------------------------------------------------------
__global__ void k_table(const float* __restrict__ Ec, const float* __restrict__ Wih,
                        const float* __restrict__ br, float* __restrict__ table) {
  __shared__ __align__(16) float e[ECH];
  int a = blockIdx.x, tid = threadIdx.x;
  if (tid < ECH) e[tid] = Ec[a * ECH + tid];
  __syncthreads();
  for (int row = tid; row < 4 * HR; row += 256) {
    const float4* w = (const float4*)(Wih + row * ECH);
    const float4* e4 = (const float4*)e;
    float acc = 0.f;
#pragma unroll
    for (int j = 0; j < ECH / 4; ++j) {
      float4 wv = w[j], ev = e4[j];
      acc += wv.x * ev.x + wv.y * ev.y + wv.z * ev.z + wv.w * ev.w;
    }
    table[a * (4 * HR) + row] = acc + br[row];
  }
}

// ---------------------------------------------------------------------------
// K1b: permute W_ih_w k-major: WT[k][p], p = wg*64 + (gate*16 + unit).
// ---------------------------------------------------------------------------
__global__ void k_permw(const float* __restrict__ Wihw, const float* __restrict__ bw,
                        float* __restrict__ WT, float* __restrict__ bperm) {
  int e = blockIdx.x * 256 + threadIdx.x;
  int p = e >> 8, k = e & 255;
  int r = p & 63, wgp = p >> 6;
  int R = (r >> 4) * HW + wgp * 16 + (r & 15);
  WT[k * (4 * HW) + p] = Wihw[R * (EW + DL) + k];
  if (k == 0) bperm[p] = bw[R];
}

// ---------------------------------------------------------------------------
// K2: persistent char LSTM. 16 WGs x 256 threads on one XCD.
// slots: [parity][replica g][slot s], slot padded to 128 B -> the line polled
// by thread (g, s) is private to that single lane.
// ---------------------------------------------------------------------------
__global__ __launch_bounds__(256, 1) void k_char_lstm(
    const int* __restrict__ char_ids, const float* __restrict__ Whh,
    const float* __restrict__ table, unsigned long long* __restrict__ slots,
    int* __restrict__ elect, float* __restrict__ h_word)
{
  __shared__ int role_sh;
  if (threadIdx.x == 0) role_sh = elect_role(elect, NWC);
  __syncthreads();
  const int wg = role_sh;
  if (wg < 0) return;

  const int tid = threadIdx.x;
  const int wave = tid >> 6, lane = tid & 63;
  const int R = (lane >> 4) * HR + wg * 16 + (lane & 15);
  float4 wreg[16];
  {
    const float4* wp = (const float4*)(Whh + R * HR + wave * 64);
#pragma unroll
    for (int j = 0; j < 16; ++j) wreg[j] = wp[j];
  }
  __shared__ __align__(16) float tab[ALPHA * 64];
  __shared__ __align__(16) float hst[4][64];
  __shared__ __align__(16) float part[2][4][64];
  for (int i = tid; i < ALPHA * 64; i += 256) {
    int chh = i >> 6, r = i & 63;
    int Rr = (r >> 4) * HR + wg * 16 + (r & 15);
    tab[i] = table[chh * (4 * HR) + Rr];
  }
  hst[wave][lane] = 0.f;
  float creg = 0.f;                      // cell state: wave0 lanes<16
  unsigned long long pr0 = 0, pr1 = 0, pr2 = 0;  // pipelined probe regs
  // poll addresses for both parities (private line per thread)
  unsigned long long* sl0 = slots + (unsigned)((0 * NWC + wg) * HR + tid) * SC_STRIDE;
  unsigned long long* sl1 = slots + (unsigned)((1 * NWC + wg) * HR + tid) * SC_STRIDE;
  __syncthreads();

#pragma unroll 1
  for (int t = 0; t < TCH; ++t) {
    int ch = char_ids[t];
    if (t > 0) {
      unsigned long long v = poll3(((t - 1) & 1) ? sl1 : sl0,
                                   ((unsigned long long)(unsigned)t) << 32,
                                   pr0, pr1, pr2);
      hst[wave][lane] = __uint_as_float((unsigned)v);
      // same-wave LDS write->read: compiler-inserted lgkmcnt, no barrier.
    }
    const float4* hp = (const float4*)hst[wave];
    float a0 = 0.f, a1 = 0.f, a2 = 0.f, a3 = 0.f;
#pragma unroll
    for (int j = 0; j < 4; ++j) {
      float4 h0 = hp[4*j+0], h1 = hp[4*j+1], h2 = hp[4*j+2], h3 = hp[4*j+3];
      float4 w0 = wreg[4*j+0], w1 = wreg[4*j+1], w2 = wreg[4*j+2], w3 = wreg[4*j+3];
      a0 += w0.x*h0.x + w0.y*h0.y + w0.z*h0.z + w0.w*h0.w;
      a1 += w1.x*h1.x + w1.y*h1.y + w1.z*h1.z + w1.w*h1.w;
      a2 += w2.x*h2.x + w2.y*h2.y + w2.z*h2.z + w2.w*h2.w;
      a3 += w3.x*h3.x + w3.y*h3.y + w3.z*h3.z + w3.w*h3.w;
    }
    const int par = t & 1;
    part[par][wave][lane] = (a0 + a1) + (a2 + a3);
    barrier_lds();                       // single barrier per step
    if (wave == 0) {
      float z = ((part[par][0][lane] + part[par][1][lane]) +
                 (part[par][2][lane] + part[par][3][lane])) + tab[ch * 64 + lane];
      int u = lane & 15;
      float zi = __shfl(z, u,      64);
      float zf = __shfl(z, u + 16, 64);
      float zg = __shfl(z, u + 32, 64);
      float zo = __shfl(z, u + 48, 64);
      float h = 0.f;
      unsigned long long pv = 0;
      if (lane < 16) {
        float ig = fsigmoid(zi), fg = fsigmoid(zf), og = fsigmoid(zo);
        float gg = ftanh(zg);
        creg = fg * creg + ig * gg;
        h = og * ftanh(creg);
        pv = (((unsigned long long)(unsigned)(t + 1)) << 32) |
             (unsigned long long)__float_as_uint(h);
      }
      // fan the 16 tagged words out to all 16 replicas (4 swaps/lane)
      unsigned long long pvb = __shfl(pv, lane & 15, 64);
      int s = wg * 16 + (lane & 15);
#pragma unroll
      for (int i = 0; i < 4; ++i) {
        int rep = (lane >> 4) + 4 * i;
        atom_swap(slots + (unsigned)((par * NWC + rep) * HR + s) * SC_STRIDE, pvb);
      }
      if ((t & 3) == 3 && lane < 16)
        h_word[(t >> 2) * HR + wg * 16 + lane] = h;
    }
  }
  drain_vm();                            // retire stray probes before endpgm
}

// ---------------------------------------------------------------------------
// K3a: latent = tanh(h_word @ W_lat^T + b_lat).
// ---------------------------------------------------------------------------
__global__ __launch_bounds__(128) void k_latent(
    const float* __restrict__ hw, const float* __restrict__ Wlat,
    const float* __restrict__ blat, float* __restrict__ lat)
{
  int t = blockIdx.x, d = threadIdx.x;
  __shared__ __align__(16) float hh[HR];
  ((float2*)hh)[d] = ((const float2*)(hw + t * HR))[d];
  __syncthreads();
  const float4* w = (const float4*)(Wlat + d * HR);
  const float4* h4 = (const float4*)hh;
  float acc = 0.f;
#pragma unroll 8
  for (int j = 0; j < HR / 4; ++j) {
    float4 wv = w[j], hv = h4[j];
    acc += wv.x * hv.x + wv.y * hv.y + wv.z * hv.z + wv.w * hv.w;
  }
  lat[t * DL + d] = tanhf(acc + blat[d]);
}

// ---------------------------------------------------------------------------
// K3b: Xw[t][p] = bperm[p] + concat(E_word[wid[t]], latent[t]) · W row(p)
// ---------------------------------------------------------------------------
__global__ __launch_bounds__(256) void k_xw(
    const float* __restrict__ Ew, const int* __restrict__ wid,
    const float* __restrict__ lat, const float* __restrict__ WT,
    const float* __restrict__ bperm, float* __restrict__ Xw)
{
  int tblk = blockIdx.x, pblk = blockIdx.y;
  int tid = threadIdx.x;
  int p = pblk * 256 + tid;
  __shared__ __align__(16) float xt[32][256];
  int t0 = tblk * 32;
  for (int i = tid; i < 32 * 256; i += 256) {
    int tl = i >> 8, e = i & 255;
    int t = t0 + tl;
    float v;
    if (e < 128) v = Ew[wid[t] * EW + e];
    else         v = lat[t * DL + (e - 128)];
    xt[tl][e] = v;
  }
  __syncthreads();
  float acc[32];
#pragma unroll
  for (int i = 0; i < 32; ++i) acc[i] = 0.f;
  for (int k = 0; k < 256; k += 4) {
    float w0 = WT[(k + 0) * (4 * HW) + p];
    float w1 = WT[(k + 1) * (4 * HW) + p];
    float w2 = WT[(k + 2) * (4 * HW) + p];
    float w3 = WT[(k + 3) * (4 * HW) + p];
#pragma unroll
    for (int tl = 0; tl < 32; ++tl) {
      float4 x4 = *(const float4*)&xt[tl][k];
      acc[tl] += w0 * x4.x + w1 * x4.y + w2 * x4.z + w3 * x4.w;
    }
  }
  float b = bperm[p];
#pragma unroll
  for (int tl = 0; tl < 32; ++tl)
    Xw[(t0 + tl) * (4 * HW) + p] = acc[tl] + b;
}

// ---------------------------------------------------------------------------
// K4: persistent word LSTM. 32 WGs x 512 threads (8 waves) on one XCD.
// slots: [parity][replica g][slot s], slot padded to 32 B (4 lanes/line).
// ---------------------------------------------------------------------------
__global__ __launch_bounds__(512, 1) void k_word_lstm(
    const float* __restrict__ Whh, const float* __restrict__ Xw,
    unsigned long long* __restrict__ slots, int* __restrict__ elect,
    float* __restrict__ out)
{
  __shared__ int role_sh;
  if (threadIdx.x == 0) role_sh = elect_role(elect, NWW);
  __syncthreads();
  const int wg = role_sh;
  if (wg < 0) return;

  const int tid = threadIdx.x;
  const int wave = tid >> 6, lane = tid & 63;
  const int R = (lane >> 4) * HW + wg * 16 + (lane & 15);
  float4 wreg[16];
  {
    const float4* wp = (const float4*)(Whh + R * HW + wave * 64);
#pragma unroll
    for (int j = 0; j < 16; ++j) wreg[j] = wp[j];
  }
  __shared__ __align__(16) float hst[8][64];
  __shared__ __align__(16) float part[2][8][64];
  hst[wave][lane] = 0.f;
  float creg = 0.f;                      // cell state: wave0 lanes<16
  unsigned long long pr0 = 0, pr1 = 0, pr2 = 0;
  unsigned long long* sl0 = slots + (unsigned)((0 * NWW + wg) * HW + tid) * SW_STRIDE;
  unsigned long long* sl1 = slots + (unsigned)((1 * NWW + wg) * HW + tid) * SW_STRIDE;
  __syncthreads();
  float xv = 0.f;
  if (wave == 0) xv = Xw[wg * 64 + lane];

#pragma unroll 1
  for (int t = 0; t < S_LEN; ++t) {
    float xn = 0.f;
    if (wave == 0) {                     // prefetch next x-slice
      int tt = (t + 1 < S_LEN) ? (t + 1) : t;
      xn = Xw[tt * (4 * HW) + wg * 64 + lane];
    }
    if (t > 0) {
      unsigned long long v = poll3(((t - 1) & 1) ? sl1 : sl0,
                                   ((unsigned long long)(unsigned)t) << 32,
                                   pr0, pr1, pr2);
      hst[wave][lane] = __uint_as_float((unsigned)v);
    }
    const float4* hp = (const float4*)hst[wave];
    float a0 = 0.f, a1 = 0.f, a2 = 0.f, a3 = 0.f;
#pragma unroll
    for (int j = 0; j < 4; ++j) {
      float4 h0 = hp[4*j+0], h1 = hp[4*j+1], h2 = hp[4*j+2], h3 = hp[4*j+3];
      float4 w0 = wreg[4*j+0], w1 = wreg[4*j+1], w2 = wreg[4*j+2], w3 = wreg[4*j+3];
      a0 += w0.x*h0.x + w0.y*h0.y + w0.z*h0.z + w0.w*h0.w;
      a1 += w1.x*h1.x + w1.y*h1.y + w1.z*h1.z + w1.w*h1.w;
      a2 += w2.x*h2.x + w2.y*h2.y + w2.z*h2.z + w2.w*h2.w;
      a3 += w3.x*h3.x + w3.y*h3.y + w3.z*h3.z + w3.w*h3.w;
    }
    const int par = t & 1;
    part[par][wave][lane] = (a0 + a1) + (a2 + a3);
    barrier_lds();
    if (wave == 0) {
      float z = (((part[par][0][lane] + part[par][1][lane]) +
                  (part[par][2][lane] + part[par][3][lane])) +
                 ((part[par][4][lane] + part[par][5][lane]) +
                  (part[par][6][lane] + part[par][7][lane]))) + xv;
      int u = lane & 15;
      float zi = __shfl(z, u,      64);
      float zf = __shfl(z, u + 16, 64);
      float zg = __shfl(z, u + 32, 64);
      float zo = __shfl(z, u + 48, 64);
      float h = 0.f;
      unsigned long long pv = 0;
      if (lane < 16) {
        float ig = fsigmoid(zi), fg = fsigmoid(zf), og = fsigmoid(zo);
        float gg = ftanh(zg);
        creg = fg * creg + ig * gg;
        h = og * ftanh(creg);
        pv = (((unsigned long long)(unsigned)(t + 1)) << 32) |
             (unsigned long long)__float_as_uint(h);
      }
      unsigned long long pvb = __shfl(pv, lane & 15, 64);
      int s = wg * 16 + (lane & 15);
#pragma unroll
      for (int i = 0; i < 8; ++i) {
        int rep = (lane >> 4) + 4 * i;
        atom_swap(slots + (unsigned)((par * NWW + rep) * HW + s) * SW_STRIDE, pvb);
      }
      if (lane < 16) out[t * HW + wg * 16 + lane] = h;
      xv = xn;
    }
  }
  drain_vm();
}

// ---------------------------------------------------------------------------
extern "C" void kernel_launch(void* const* d_in, const int* in_sizes, int n_in,
                              void* d_out, int out_size, void* d_ws, size_t ws_size,
                              hipStream_t stream) {
  const float* E_char = (const float*)d_in[0];
  const float* W_ih_r = (const float*)d_in[1];
  const float* W_hh_r = (const float*)d_in[2];
  const float* b_r    = (const float*)d_in[3];
  const float* W_lat  = (const float*)d_in[4];
  const float* b_lat  = (const float*)d_in[5];
  const float* E_word = (const float*)d_in[6];
  const float* W_ih_w = (const float*)d_in[7];
  const float* W_hh_w = (const float*)d_in[8];
  const float* b_w    = (const float*)d_in[9];
  const int* word_ids = (const int*)d_in[10];
  const int* char_ids = (const int*)d_in[11];

  char* ws = (char*)d_ws;
  float*              tableR = (float*)(ws + 0x000000);              // 100 KB
  int*                electC = (int*)(ws + 0x020000);
  int*                electW = (int*)(ws + 0x020100);
  unsigned long long* slotC  = (unsigned long long*)(ws + 0x030000); // 1 MB
  unsigned long long* slotW  = (unsigned long long*)(ws + 0x130000); // 1 MB
  float*              h_word = (float*)(ws + 0x230000);              // 4 MB
  float*              latent = (float*)(ws + 0x630000);              // 2 MB
  float*              WT     = (float*)(ws + 0x830000);              // 2 MB
  float*              bperm  = (float*)(ws + 0xA30000);              // 8 KB
  float*              Xw     = (float*)(ws + 0xA40000);              // 32 MB
  float* out = (float*)d_out;

  hipLaunchKernelGGL(k_zero,      dim3(512),    dim3(256), 0, stream,
                     (float4*)(ws + 0x030000));                      // 2 MB slots
  hipLaunchKernelGGL(k_init,      dim3(1),      dim3(64),  0, stream,
                     electC, electW);
  hipLaunchKernelGGL(k_table,     dim3(ALPHA),  dim3(256), 0, stream,
                     E_char, W_ih_r, b_r, tableR);
  hipLaunchKernelGGL(k_permw,     dim3(2048),   dim3(256), 0, stream,
                     W_ih_w, b_w, WT, bperm);
  hipLaunchKernelGGL(k_char_lstm, dim3(GRIDC),  dim3(256), 0, stream,
                     char_ids, W_hh_r, tableR, slotC, electC, h_word);
  hipLaunchKernelGGL(k_latent,    dim3(S_LEN),  dim3(128), 0, stream,
                     h_word, W_lat, b_lat, latent);
  hipLaunchKernelGGL(k_xw,        dim3(128, 8), dim3(256), 0, stream,
                     E_word, word_ids, latent, WT, bperm, Xw);
  hipLaunchKernelGGL(k_word_lstm, dim3(GRIDW),  dim3(512), 0, stream,
                     W_hh_w, Xw, slotW, electW, out);
}

// Round 9
// 42855.096 us; speedup vs baseline: 1.4878x; 1.4878x over previous
//
#include <hip/hip_runtime.h>

// ============================================================================
// Two-level LSTM (char k-mer LSTM -> word LSTM), MI355X.
//
// Persistent multi-WG recurrence kernels, all worker WGs elected onto ONE XCD.
// R8 lesson: the exchange floor is TCC atomic-RMW THROUGHPUT (~4096 probes/
// round ~= 3000 cyc), not latency or line-sharing. R9 protocol:
//   - publish: 16 tag-embedded words/WG ((t+1)<<32 | f32bits(h)) swapped into
//     a 256-deep ROTATING buffer (global_atomic_swap_x2 -> data committed at
//     the TCC, immune to the write-back-L1 trap that broke R5). 256 swaps/
//     step total. Single-hop: tag and data travel together, no drain needed.
//   - poll: every consumer thread LOAD-polls its own word with
//     `global_load_dwordx2 sc0 nt` (L1-bypass hint; rotating address is
//     L1-cold on first touch) + exact-tag check. Loads are not RMWs -> no
//     TCC serialization. Every 4th probe is an atomic or-0 (architecturally
//     coherent) so a stale-L1 pathology degrades to ~R7 perf, never a hang.
//   - exact tag match (== t) is 0xAA-poison-safe -> no zero kernel.
// Skeleton (elect-one-XCD, parity-buffered part[], single LDS barrier/step,
// launch_bounds(...,1)) carried from R7.
// ============================================================================

#define S_LEN 4096
#define TCH   16384
#define ALPHA 25
#define ECH   64
#define HR    256
#define DL    128
#define EW    128
#define HW    512
#define NWC   16           // char worker WGs (16 units each)
#define GRIDC 128
#define NWW   32           // word worker WGs (16 units each)
#define GRIDW 256
#define NBUF  256          // rotation depth (slots reused every 256 steps)

static __device__ __forceinline__ float fsigmoid(float x) {
  x = fminf(fmaxf(x, -30.f), 30.f);
  return __builtin_amdgcn_rcpf(1.0f + __expf(-x));
}
static __device__ __forceinline__ float ftanh(float x) {
  x = fminf(fmaxf(x, -15.f), 15.f);
  float e = __expf(2.0f * x);
  return 1.0f - 2.0f * __builtin_amdgcn_rcpf(e + 1.0f);
}

static __device__ __forceinline__ void barrier_lds() {
  asm volatile("s_waitcnt lgkmcnt(0)\n\ts_barrier" ::: "memory");
}
static __device__ __forceinline__ void drain_vm() {
  asm volatile("s_waitcnt vmcnt(0)" ::: "memory");
}
// Load-probe: sc0+nt global load (L1-bypass / non-temporal), no RMW cost.
static __device__ __forceinline__ unsigned long long load_probe(
    const unsigned long long* p) {
  unsigned long long v;
  asm volatile("global_load_dwordx2 %0, %1, off sc0 nt\n\ts_waitcnt vmcnt(0)"
               : "=v"(v) : "v"(p));
  return v;
}
// Atomic or-0 with return: executed at the TCC, architecturally coherent.
static __device__ __forceinline__ unsigned long long atom_or_ret(
    unsigned long long* p) {
  unsigned long long v, zero = 0;
  asm volatile("global_atomic_or_x2 %0, %1, %2, off sc0\n\ts_waitcnt vmcnt(0)"
               : "=&v"(v) : "v"(p), "v"(zero));
  return v;
}
// Publish: fire-and-forget swap; data+tag land at the TCC together.
static __device__ __forceinline__ void atom_swap(
    unsigned long long* p, unsigned long long v) {
  asm volatile("global_atomic_swap_x2 %0, %1, off" :: "v"(p), "v"(v));
}

// Combined poll: 3 load-probes, then 1 atomic probe, repeat.
static __device__ __forceinline__ unsigned long long poll_slot(
    unsigned long long* p, unsigned tag) {
  unsigned long long v;
  for (;;) {
#pragma unroll
    for (int k = 0; k < 3; ++k) {
      v = load_probe(p);
      if ((unsigned)(v >> 32) == tag) return v;
    }
    v = atom_or_ret(p);
    if ((unsigned)(v >> 32) == tag) return v;
  }
}

// Deadlock-free single-XCD role election (R4-proven).
static __device__ __forceinline__ int elect_role(int* el, int NW) {
  unsigned xcd;
  asm volatile("s_getreg_b32 %0, hwreg(HW_REG_XCC_ID)" : "=s"(xcd));
  xcd &= 7u;
  int r = __hip_atomic_fetch_add(&el[xcd], 1, __ATOMIC_RELAXED,
                                 __HIP_MEMORY_SCOPE_AGENT);
  if (r == NW - 1) {
    int exp = -1;
    __hip_atomic_compare_exchange_strong(&el[8], &exp, (int)xcd,
        __ATOMIC_RELAXED, __ATOMIC_RELAXED, __HIP_MEMORY_SCOPE_AGENT);
  }
  int w;
  while ((w = __hip_atomic_load(&el[8], __ATOMIC_RELAXED,
                                __HIP_MEMORY_SCOPE_AGENT)) < 0) {}
  if (w != (int)xcd) return -1;
  int rr = __hip_atomic_fetch_add(&el[9], 1, __ATOMIC_RELAXED,
                                  __HIP_MEMORY_SCOPE_AGENT);
  return (rr < NW) ? rr : -1;
}

__global__ void k_init(int* ec, int* ew) {
  int t = threadIdx.x;
  if (t < 10) ec[t] = (t == 8) ? -1 : 0;
  else if (t < 20) { int u = t - 10; ew[u] = (u == 8) ? -1 : 0; }
}

// ---------------------------------------------------------------------------
// K1a: char gate-input table.
// ---------------------------------------------------------------------------
__global__ void k_table(const float* __restrict__ Ec, const float* __restrict__ Wih,
                        const float* __restrict__ br, float* __restrict__ table) {
  __shared__ __align__(16) float e[ECH];
  int a = blockIdx.x, tid = threadIdx.x;
  if (tid < ECH) e[tid] = Ec[a * ECH + tid];
  __syncthreads();
  for (int row = tid; row < 4 * HR; row += 256) {
    const float4* w = (const float4*)(Wih + row * ECH);
    const float4* e4 = (const float4*)e;
    float acc = 0.f;
#pragma unroll
    for (int j = 0; j < ECH / 4; ++j) {
      float4 wv = w[j], ev = e4[j];
      acc += wv.x * ev.x + wv.y * ev.y + wv.z * ev.z + wv.w * ev.w;
    }
    table[a * (4 * HR) + row] = acc + br[row];
  }
}

// ---------------------------------------------------------------------------
// K1b: permute W_ih_w k-major: WT[k][p], p = wg*64 + (gate*16 + unit).
// ---------------------------------------------------------------------------
__global__ void k_permw(const float* __restrict__ Wihw, const float* __restrict__ bw,
                        float* __restrict__ WT, float* __restrict__ bperm) {
  int e = blockIdx.x * 256 + threadIdx.x;
  int p = e >> 8, k = e & 255;
  int r = p & 63, wgp = p >> 6;
  int R = (r >> 4) * HW + wgp * 16 + (r & 15);
  WT[k * (4 * HW) + p] = Wihw[R * (EW + DL) + k];
  if (k == 0) bperm[p] = bw[R];
}

// ---------------------------------------------------------------------------
// K2: persistent char LSTM. 16 WGs x 256 threads on one XCD.
// hbuf: [slot = t & 255][h index 0..255], tag-embedded u64 each.
// ---------------------------------------------------------------------------
__global__ __launch_bounds__(256, 1) void k_char_lstm(
    const int* __restrict__ char_ids, const float* __restrict__ Whh,
    const float* __restrict__ table, unsigned long long* __restrict__ hbuf,
    int* __restrict__ elect, float* __restrict__ h_word)
{
  __shared__ int role_sh;
  if (threadIdx.x == 0) role_sh = elect_role(elect, NWC);
  __syncthreads();
  const int wg = role_sh;
  if (wg < 0) return;

  const int tid = threadIdx.x;
  const int wave = tid >> 6, lane = tid & 63;
  const int R = (lane >> 4) * HR + wg * 16 + (lane & 15);
  float4 wreg[16];
  {
    const float4* wp = (const float4*)(Whh + R * HR + wave * 64);
#pragma unroll
    for (int j = 0; j < 16; ++j) wreg[j] = wp[j];
  }
  __shared__ __align__(16) float tab[ALPHA * 64];
  __shared__ __align__(16) float hst[4][64];
  __shared__ __align__(16) float part[2][4][64];
  for (int i = tid; i < ALPHA * 64; i += 256) {
    int chh = i >> 6, r = i & 63;
    int Rr = (r >> 4) * HR + wg * 16 + (r & 15);
    tab[i] = table[chh * (4 * HR) + Rr];
  }
  hst[wave][lane] = 0.f;
  float creg = 0.f;                      // cell state: wave0 lanes<16
  __syncthreads();

#pragma unroll 1
  for (int t = 0; t < TCH; ++t) {
    int ch = char_ids[t];
    if (t > 0) {
      // poll own tag-embedded word in the rotating slot of step t-1
      unsigned long long v =
          poll_slot(hbuf + ((t - 1) & (NBUF - 1)) * HR + tid, (unsigned)t);
      hst[wave][lane] = __uint_as_float((unsigned)v);
      // same-wave LDS write->read: compiler-inserted lgkmcnt, no barrier.
    }
    const float4* hp = (const float4*)hst[wave];
    float a0 = 0.f, a1 = 0.f, a2 = 0.f, a3 = 0.f;
#pragma unroll
    for (int j = 0; j < 4; ++j) {
      float4 h0 = hp[4*j+0], h1 = hp[4*j+1], h2 = hp[4*j+2], h3 = hp[4*j+3];
      float4 w0 = wreg[4*j+0], w1 = wreg[4*j+1], w2 = wreg[4*j+2], w3 = wreg[4*j+3];
      a0 += w0.x*h0.x + w0.y*h0.y + w0.z*h0.z + w0.w*h0.w;
      a1 += w1.x*h1.x + w1.y*h1.y + w1.z*h1.z + w1.w*h1.w;
      a2 += w2.x*h2.x + w2.y*h2.y + w2.z*h2.z + w2.w*h2.w;
      a3 += w3.x*h3.x + w3.y*h3.y + w3.z*h3.z + w3.w*h3.w;
    }
    const int par = t & 1;
    part[par][wave][lane] = (a0 + a1) + (a2 + a3);
    barrier_lds();                       // single barrier per step
    if (wave == 0) {
      float z = ((part[par][0][lane] + part[par][1][lane]) +
                 (part[par][2][lane] + part[par][3][lane])) + tab[ch * 64 + lane];
      int u = lane & 15;
      float zi = __shfl(z, u,      64);
      float zf = __shfl(z, u + 16, 64);
      float zg = __shfl(z, u + 32, 64);
      float zo = __shfl(z, u + 48, 64);
      if (lane < 16) {
        float ig = fsigmoid(zi), fg = fsigmoid(zf), og = fsigmoid(zo);
        float gg = ftanh(zg);
        creg = fg * creg + ig * gg;
        float h = og * ftanh(creg);
        unsigned long long pv =
            (((unsigned long long)(unsigned)(t + 1)) << 32) |
            (unsigned long long)__float_as_uint(h);
        atom_swap(hbuf + (t & (NBUF - 1)) * HR + wg * 16 + lane, pv);
        if ((t & 3) == 3)
          h_word[(t >> 2) * HR + wg * 16 + lane] = h;
      }
    }
  }
  drain_vm();
}

// ---------------------------------------------------------------------------
// K3a: latent = tanh(h_word @ W_lat^T + b_lat).
// ---------------------------------------------------------------------------
__global__ __launch_bounds__(128) void k_latent(
    const float* __restrict__ hw, const float* __restrict__ Wlat,
    const float* __restrict__ blat, float* __restrict__ lat)
{
  int t = blockIdx.x, d = threadIdx.x;
  __shared__ __align__(16) float hh[HR];
  ((float2*)hh)[d] = ((const float2*)(hw + t * HR))[d];
  __syncthreads();
  const float4* w = (const float4*)(Wlat + d * HR);
  const float4* h4 = (const float4*)hh;
  float acc = 0.f;
#pragma unroll 8
  for (int j = 0; j < HR / 4; ++j) {
    float4 wv = w[j], hv = h4[j];
    acc += wv.x * hv.x + wv.y * hv.y + wv.z * hv.z + wv.w * hv.w;
  }
  lat[t * DL + d] = tanhf(acc + blat[d]);
}

// ---------------------------------------------------------------------------
// K3b: Xw[t][p] = bperm[p] + concat(E_word[wid[t]], latent[t]) · W row(p)
// ---------------------------------------------------------------------------
__global__ __launch_bounds__(256) void k_xw(
    const float* __restrict__ Ew, const int* __restrict__ wid,
    const float* __restrict__ lat, const float* __restrict__ WT,
    const float* __restrict__ bperm, float* __restrict__ Xw)
{
  int tblk = blockIdx.x, pblk = blockIdx.y;
  int tid = threadIdx.x;
  int p = pblk * 256 + tid;
  __shared__ __align__(16) float xt[32][256];
  int t0 = tblk * 32;
  for (int i = tid; i < 32 * 256; i += 256) {
    int tl = i >> 8, e = i & 255;
    int t = t0 + tl;
    float v;
    if (e < 128) v = Ew[wid[t] * EW + e];
    else         v = lat[t * DL + (e - 128)];
    xt[tl][e] = v;
  }
  __syncthreads();
  float acc[32];
#pragma unroll
  for (int i = 0; i < 32; ++i) acc[i] = 0.f;
  for (int k = 0; k < 256; k += 4) {
    float w0 = WT[(k + 0) * (4 * HW) + p];
    float w1 = WT[(k + 1) * (4 * HW) + p];
    float w2 = WT[(k + 2) * (4 * HW) + p];
    float w3 = WT[(k + 3) * (4 * HW) + p];
#pragma unroll
    for (int tl = 0; tl < 32; ++tl) {
      float4 x4 = *(const float4*)&xt[tl][k];
      acc[tl] += w0 * x4.x + w1 * x4.y + w2 * x4.z + w3 * x4.w;
    }
  }
  float b = bperm[p];
#pragma unroll
  for (int tl = 0; tl < 32; ++tl)
    Xw[(t0 + tl) * (4 * HW) + p] = acc[tl] + b;
}

// ---------------------------------------------------------------------------
// K4: persistent word LSTM. 32 WGs x 512 threads (8 waves) on one XCD.
// hbuf: [slot = t & 255][h index 0..511].
// ---------------------------------------------------------------------------
__global__ __launch_bounds__(512, 1) void k_word_lstm(
    const float* __restrict__ Whh, const float* __restrict__ Xw,
    unsigned long long* __restrict__ hbuf, int* __restrict__ elect,
    float* __restrict__ out)
{
  __shared__ int role_sh;
  if (threadIdx.x == 0) role_sh = elect_role(elect, NWW);
  __syncthreads();
  const int wg = role_sh;
  if (wg < 0) return;

  const int tid = threadIdx.x;
  const int wave = tid >> 6, lane = tid & 63;
  const int R = (lane >> 4) * HW + wg * 16 + (lane & 15);
  float4 wreg[16];
  {
    const float4* wp = (const float4*)(Whh + R * HW + wave * 64);
#pragma unroll
    for (int j = 0; j < 16; ++j) wreg[j] = wp[j];
  }
  __shared__ __align__(16) float hst[8][64];
  __shared__ __align__(16) float part[2][8][64];
  hst[wave][lane] = 0.f;
  float creg = 0.f;                      // cell state: wave0 lanes<16
  __syncthreads();
  float xv = 0.f;
  if (wave == 0) xv = Xw[wg * 64 + lane];

#pragma unroll 1
  for (int t = 0; t < S_LEN; ++t) {
    float xn = 0.f;
    if (wave == 0) {                     // prefetch next x-slice
      int tt = (t + 1 < S_LEN) ? (t + 1) : t;
      xn = Xw[tt * (4 * HW) + wg * 64 + lane];
    }
    if (t > 0) {
      unsigned long long v =
          poll_slot(hbuf + ((t - 1) & (NBUF - 1)) * HW + tid, (unsigned)t);
      hst[wave][lane] = __uint_as_float((unsigned)v);
    }
    const float4* hp = (const float4*)hst[wave];
    float a0 = 0.f, a1 = 0.f, a2 = 0.f, a3 = 0.f;
#pragma unroll
    for (int j = 0; j < 4; ++j) {
      float4 h0 = hp[4*j+0], h1 = hp[4*j+1], h2 = hp[4*j+2], h3 = hp[4*j+3];
      float4 w0 = wreg[4*j+0], w1 = wreg[4*j+1], w2 = wreg[4*j+2], w3 = wreg[4*j+3];
      a0 += w0.x*h0.x + w0.y*h0.y + w0.z*h0.z + w0.w*h0.w;
      a1 += w1.x*h1.x + w1.y*h1.y + w1.z*h1.z + w1.w*h1.w;
      a2 += w2.x*h2.x + w2.y*h2.y + w2.z*h2.z + w2.w*h2.w;
      a3 += w3.x*h3.x + w3.y*h3.y + w3.z*h3.z + w3.w*h3.w;
    }
    const int par = t & 1;
    part[par][wave][lane] = (a0 + a1) + (a2 + a3);
    barrier_lds();
    if (wave == 0) {
      float z = (((part[par][0][lane] + part[par][1][lane]) +
                  (part[par][2][lane] + part[par][3][lane])) +
                 ((part[par][4][lane] + part[par][5][lane]) +
                  (part[par][6][lane] + part[par][7][lane]))) + xv;
      int u = lane & 15;
      float zi = __shfl(z, u,      64);
      float zf = __shfl(z, u + 16, 64);
      float zg = __shfl(z, u + 32, 64);
      float zo = __shfl(z, u + 48, 64);
      if (lane < 16) {
        float ig = fsigmoid(zi), fg = fsigmoid(zf), og = fsigmoid(zo);
        float gg = ftanh(zg);
        creg = fg * creg + ig * gg;
        float h = og * ftanh(creg);
        unsigned long long pv =
            (((unsigned long long)(unsigned)(t + 1)) << 32) |
            (unsigned long long)__float_as_uint(h);
        atom_swap(hbuf + (t & (NBUF - 1)) * HW + wg * 16 + lane, pv);
        out[t * HW + wg * 16 + lane] = h;
      }
      xv = xn;
    }
  }
  drain_vm();
}

// ---------------------------------------------------------------------------
extern "C" void kernel_launch(void* const* d_in, const int* in_sizes, int n_in,
                              void* d_out, int out_size, void* d_ws, size_t ws_size,
                              hipStream_t stream) {
  const float* E_char = (const float*)d_in[0];
  const float* W_ih_r = (const float*)d_in[1];
  const float* W_hh_r = (const float*)d_in[2];
  const float* b_r    = (const float*)d_in[3];
  const float* W_lat  = (const float*)d_in[4];
  const float* b_lat  = (const float*)d_in[5];
  const float* E_word = (const float*)d_in[6];
  const float* W_ih_w = (const float*)d_in[7];
  const float* W_hh_w = (const float*)d_in[8];
  const float* b_w    = (const float*)d_in[9];
  const int* word_ids = (const int*)d_in[10];
  const int* char_ids = (const int*)d_in[11];

  char* ws = (char*)d_ws;
  float*              tableR = (float*)(ws + 0x000000);              // 100 KB
  int*                electC = (int*)(ws + 0x020000);
  int*                electW = (int*)(ws + 0x020100);
  unsigned long long* hbufC  = (unsigned long long*)(ws + 0x030000); // 512 KB
  unsigned long long* hbufW  = (unsigned long long*)(ws + 0x0B0000); // 1 MB
  float*              h_word = (float*)(ws + 0x1B0000);              // 4 MB
  float*              latent = (float*)(ws + 0x5B0000);              // 2 MB
  float*              WT     = (float*)(ws + 0x7B0000);              // 2 MB
  float*              bperm  = (float*)(ws + 0x9B0000);              // 8 KB
  float*              Xw     = (float*)(ws + 0xA00000);              // 32 MB
  float* out = (float*)d_out;

  hipLaunchKernelGGL(k_init,      dim3(1),      dim3(64),  0, stream,
                     electC, electW);
  hipLaunchKernelGGL(k_table,     dim3(ALPHA),  dim3(256), 0, stream,
                     E_char, W_ih_r, b_r, tableR);
  hipLaunchKernelGGL(k_permw,     dim3(2048),   dim3(256), 0, stream,
                     W_ih_w, b_w, WT, bperm);
  hipLaunchKernelGGL(k_char_lstm, dim3(GRIDC),  dim3(256), 0, stream,
                     char_ids, W_hh_r, tableR, hbufC, electC, h_word);
  hipLaunchKernelGGL(k_latent,    dim3(S_LEN),  dim3(128), 0, stream,
                     h_word, W_lat, b_lat, latent);
  hipLaunchKernelGGL(k_xw,        dim3(128, 8), dim3(256), 0, stream,
                     E_word, word_ids, latent, WT, bperm, Xw);
  hipLaunchKernelGGL(k_word_lstm, dim3(GRIDW),  dim3(512), 0, stream,
                     W_hh_w, Xw, hbufW, electW, out);
}